// Round 1
// baseline (678.275 us; speedup 1.0000x reference)
//
#include <hip/hip_runtime.h>
#include <hip/hip_bf16.h>

// Problem constants
#define H_ 8
#define D_ 512
#define DK_ 64
#define B_ 16
#define N_ 8192
#define M_ (B_ * N_)  // 131072 rows

typedef __attribute__((ext_vector_type(8))) short short8;
typedef __attribute__((ext_vector_type(4))) float floatx4;

// ---------------------------------------------------------------- helpers
__device__ __forceinline__ void glds16(const void* g, void* l) {
    // 16B-wide direct global->LDS DMA. LDS dest = wave-uniform base + lane*16.
    __builtin_amdgcn_global_load_lds((const __attribute__((address_space(1))) void*)g,
                                     (__attribute__((address_space(3))) void*)l,
                                     16, 0, 0);
}

__device__ __forceinline__ unsigned short f2bf(float f) {  // RNE
    unsigned u = __float_as_uint(f);
    return (unsigned short)((u + 0x7fffu + ((u >> 16) & 1u)) >> 16);
}

// pack two fp32 -> two bf16 (round-half-up): low16 = bf(x), high16 = bf(y)
__device__ __forceinline__ unsigned pack_bf2(float x, float y) {
    return __builtin_amdgcn_perm(__float_as_uint(y) + 0x8000u,
                                 __float_as_uint(x) + 0x8000u, 0x07060302u);
}

__device__ __forceinline__ short8 pack_bf8(float4 lo, float4 hi) {
    union { unsigned u[4]; short8 s; } tmp;
    tmp.u[0] = pack_bf2(lo.x, lo.y);
    tmp.u[1] = pack_bf2(lo.z, lo.w);
    tmp.u[2] = pack_bf2(hi.x, hi.y);
    tmp.u[3] = pack_bf2(hi.z, hi.w);
    return tmp.s;
}

// ---------------------------------------------------------------- kernel 0: fp32 -> bf16 (weights only, 1 MB total)
__global__ __launch_bounds__(256) void cvt_kernel(const float* __restrict__ src,
                                                  unsigned short* __restrict__ dst, int n4) {
    int i = blockIdx.x * blockDim.x + threadIdx.x;
    int stride = gridDim.x * blockDim.x;
    for (; i < n4; i += stride) {
        float4 v = ((const float4*)src)[i];
        ushort4 o;
        o.x = f2bf(v.x); o.y = f2bf(v.y); o.z = f2bf(v.z); o.w = f2bf(v.w);
        ((ushort4*)dst)[i] = o;
    }
}

// ---------------------------------------------------------------- kernel 1: fused double-GEMM + gate + query-dot
// 8-phase-per-K-tile schedule (T2+T3/T4+T5):
//   BM=256 rows, 128 cols of BOTH Wk and Wg (256 virtual cols), BK=64.
//   512 threads = 8 waves (wm in {0,1}, wn in {0..3}); wave tile = 128 rows x
//   (32 Wk-cols + 32 Wg-cols); acc = 128 VGPR.
//   LDS: double-buffered A (2x32KB) + B (2x32KB) = 128 KB, 1 block/CU.
//   Swizzle: 16B chunk q of row r stored at slot q ^ (r&7) (both A and B).
//   Per K-tile, 4 phases: {4 ds_read_b128 [+8 B-frag reads in p0; +16 VMEM
//   staging issues in p0], s_barrier, setprio(1), 16 MFMA, setprio(0),
//   s_barrier}; A pack+ds_write after p3's MFMA; single vmcnt drain per tile
//   at the tile-end __syncthreads (issue->drain distance = 3 phases).
__global__ __launch_bounds__(512, 2) void gemm_score_kernel(
    const float* __restrict__ x,             // (M_, 512) fp32
    const unsigned short* __restrict__ wkb,  // (512, 512) bf16
    const unsigned short* __restrict__ wgb,  // (512, 512) bf16
    const float* __restrict__ query,         // (8, 64) fp32
    float* __restrict__ s_buf)               // (B_, H_, N_) fp32
{
    __shared__ __attribute__((aligned(16))) unsigned short lds_a[2][256 * 64];  // 64 KB
    __shared__ __attribute__((aligned(16))) unsigned short lds_b[2][256 * 64];  // 64 KB

    const int t = threadIdx.x;
    const int lane = t & 63;
    const int wave = t >> 6;
    const int wm = wave >> 2;   // 0..1  (row half)
    const int wn = wave & 3;    // 0..3  (col quarter)
    const int fr = lane & 15;
    const int q4 = lane >> 4;
    const int sw = fr & 7;

    // XCD-aware remap: 4 jc-siblings of an m-tile -> ids 8 apart -> same XCD.
    const int g = blockIdx.x;          // 0..2047
    const int xcd = g & 7;
    const int s = g >> 3;              // 0..255
    const int jt = s & 3;              // col tile 0..3 (128 cols of each W)
    const int mt = ((s >> 2) << 3) | xcd;  // 0..511
    const int jc = jt * 128;
    const int m0 = mt * 256;

    // ---- A staging: sweep it(0..3): row = it*64 + (t>>3), float chunk (t&7)
    const int ar = t >> 3;   // 0..63
    const int ac = t & 7;    // 0..7
    const float* pA = x + (size_t)(m0 + ar) * 512 + ac * 8;
    const int asw = ac ^ (ar & 7);                 // swizzled chunk slot
    const int awoff = ar * 64 + asw * 8;           // shorts; + it*4096

    // ---- B staging: issue i: virtual col v = i*64 + ar; src chunk = ac ^ (v&7)
    const unsigned short* pB[4];
    pB[0] = wkb + (size_t)(jc + ar) * 512 + asw * 8;
    pB[1] = wkb + (size_t)(jc + 64 + ar) * 512 + asw * 8;
    pB[2] = wgb + (size_t)(jc + ar) * 512 + asw * 8;
    pB[3] = wgb + (size_t)(jc + 64 + ar) * 512 + asw * 8;

    // ---- fragment read offsets (shorts). chunk q = kk*4 + q4, slot = q^(row&7).
    const int aroff  = (wm * 128 + fr) * 64 + (q4 ^ sw) * 8;  // + mi*1024; kk=1: ^32
    const int bk_off = (wn * 32 + fr) * 64 + (q4 ^ sw) * 8;   // + ni*1024
    const int bg_off = bk_off + 128 * 64;                     // Wg half (v += 128)

    floatx4 acc_k[8][2], acc_g[8][2];
#pragma unroll
    for (int mi = 0; mi < 8; ++mi)
#pragma unroll
        for (int ni = 0; ni < 2; ++ni) { acc_k[mi][ni] = (floatx4)0.f; acc_g[mi][ni] = (floatx4)0.f; }

    float4 av[8];

    // ---- prologue: stage K-tile 0
    {
#pragma unroll
        for (int it = 0; it < 4; ++it) {
            const float* p = pA + (size_t)it * (64 * 512);
            av[it * 2]     = *(const float4*)(p);
            av[it * 2 + 1] = *(const float4*)(p + 4);
        }
#pragma unroll
        for (int i = 0; i < 4; ++i)
            glds16(pB[i], &lds_b[0][(i * 512 + wave * 64) * 8]);
#pragma unroll
        for (int it = 0; it < 4; ++it)
            *(short8*)&lds_a[0][it * 4096 + awoff] = pack_bf8(av[it * 2], av[it * 2 + 1]);
    }
    __syncthreads();

    // ---- main K loop: 8 tiles of BK=64
    for (int kt = 0; kt < 8; ++kt) {
        const int cur = kt & 1, nxt = cur ^ 1;
        const unsigned short* la = lds_a[cur];
        const unsigned short* lb = lds_b[cur];
        const int k0n = (kt + 1) * 64;
        short8 bk[2][2], bg[2][2];

#pragma unroll
        for (int p = 0; p < 4; ++p) {
            // per-phase A fragments (mi = 2p, 2p+1)
            short8 a2[2][2];
#pragma unroll
            for (int e = 0; e < 2; ++e) {
                const int mi = p * 2 + e;
                a2[e][0] = *(const short8*)&la[mi * 1024 + aroff];
                a2[e][1] = *(const short8*)&la[(mi * 1024 + aroff) ^ 32];
            }
            if (p == 0) {
                // B fragments for the whole K-tile (held in regs across phases)
#pragma unroll
                for (int ni = 0; ni < 2; ++ni) {
                    bk[ni][0] = *(const short8*)&lb[ni * 1024 + bk_off];
                    bk[ni][1] = *(const short8*)&lb[(ni * 1024 + bk_off) ^ 32];
                    bg[ni][0] = *(const short8*)&lb[ni * 1024 + bg_off];
                    bg[ni][1] = *(const short8*)&lb[(ni * 1024 + bg_off) ^ 32];
                }
                if (kt < 7) {
                    // issue ALL next-tile staging here: A fp32 loads first
                    // (older -> compiler's av-wait leaves glds16 in flight),
                    // then B glds16. Drained 3 phases later at __syncthreads.
#pragma unroll
                    for (int it = 0; it < 4; ++it) {
                        const float* pp = pA + (size_t)it * (64 * 512) + k0n;
                        av[it * 2]     = *(const float4*)(pp);
                        av[it * 2 + 1] = *(const float4*)(pp + 4);
                    }
#pragma unroll
                    for (int i = 0; i < 4; ++i)
                        glds16(pB[i] + k0n, &lds_b[nxt][(i * 512 + wave * 64) * 8]);
                }
            }
            __builtin_amdgcn_s_barrier();
            __builtin_amdgcn_s_setprio(1);
#pragma unroll
            for (int e = 0; e < 2; ++e) {
                const int mi = p * 2 + e;
#pragma unroll
                for (int ni = 0; ni < 2; ++ni) {
#pragma unroll
                    for (int kk = 0; kk < 2; ++kk) {
                        acc_k[mi][ni] = __builtin_amdgcn_mfma_f32_16x16x32_bf16(a2[e][kk], bk[ni][kk], acc_k[mi][ni], 0, 0, 0);
                        acc_g[mi][ni] = __builtin_amdgcn_mfma_f32_16x16x32_bf16(a2[e][kk], bg[ni][kk], acc_g[mi][ni], 0, 0, 0);
                    }
                }
            }
            __builtin_amdgcn_s_setprio(0);
            if (p == 3 && kt < 7) {
                // A pack + swizzled ds_write into next buffer, after the MFMAs
                // so the vmcnt wait for av doesn't block the matrix pipe.
#pragma unroll
                for (int it = 0; it < 4; ++it)
                    *(short8*)&lds_a[nxt][it * 4096 + awoff] = pack_bf8(av[it * 2], av[it * 2 + 1]);
            }
            if (p < 3) __builtin_amdgcn_s_barrier();
        }
        __syncthreads();  // drains glds16 (issued in p0) + A ds_writes, publishes nxt
    }

    // ---- epilogue: gated = tanh(K)*sigmoid(G); score = q . gated.
    // C/D layout: col = lane&15 (weight col), row = (lane>>4)*4 + reg (x row).
    // Wave (wm,wn) holds cols d = (wn&1)*32 + ni*16 + fr of head jt*2+(wn>>1);
    // partial over 32 d per wave -> combine wave pairs via LDS.
    float* part = (float*)&lds_a[0][0];  // [4][256] floats, reuse LDS
    const int h = jt * 2 + (wn >> 1);
    const int dbase = (wn & 1) * 32;
    float qv[2];
    qv[0] = query[h * 64 + dbase + fr];
    qv[1] = query[h * 64 + dbase + 16 + fr];

#pragma unroll
    for (int mi = 0; mi < 8; ++mi) {
#pragma unroll
        for (int r = 0; r < 4; ++r) {
            float v = 0.f;
#pragma unroll
            for (int ni = 0; ni < 2; ++ni) {
                float kv = acc_k[mi][ni][r];
                float gv = acc_g[mi][ni][r];
                float e2k = __expf(2.f * kv);
                float th = 1.f - 2.f / (e2k + 1.f);       // tanh, overflow-safe
                float sg = 1.f / (1.f + __expf(-gv));     // sigmoid
                v += qv[ni] * th * sg;
            }
            v += __shfl_xor(v, 1);
            v += __shfl_xor(v, 2);
            v += __shfl_xor(v, 4);
            v += __shfl_xor(v, 8);
            if (fr == 0)
                part[wn * 256 + wm * 128 + mi * 16 + q4 * 4 + r] = v;
        }
    }
    __syncthreads();
    {
        const int hw = t >> 8;       // 0..1: head within this block's pair
        const int row = t & 255;
        float val = part[(hw * 2) * 256 + row] + part[(hw * 2 + 1) * 256 + row];
        int m = m0 + row;
        int b = m >> 13, n = m & 8191;
        s_buf[((size_t)(b * 8 + jt * 2 + hw) << 13) + n] = val;
    }
}

// ---------------------------------------------------------------- kernel 2: per-(b,h) softmax stats (float4, values kept in regs)
__global__ __launch_bounds__(256) void stats_kernel(const float* __restrict__ s_buf,
                                                    float* __restrict__ mb, float* __restrict__ lb) {
    const int bh = blockIdx.x;  // 0..127
    const float4* s4 = (const float4*)(s_buf + ((size_t)bh << 13));
    const int t = threadIdx.x;
    float4 vv[8];
    float mx = -3.0e38f;
#pragma unroll
    for (int i = 0; i < 8; ++i) {
        float4 v = s4[t + i * 256];
        vv[i] = v;
        mx = fmaxf(mx, fmaxf(fmaxf(v.x, v.y), fmaxf(v.z, v.w)));
    }
#pragma unroll
    for (int m = 32; m > 0; m >>= 1) mx = fmaxf(mx, __shfl_xor(mx, m));
    __shared__ float red[8];
    if ((t & 63) == 0) red[t >> 6] = mx;
    __syncthreads();
    mx = fmaxf(fmaxf(red[0], red[1]), fmaxf(red[2], red[3]));
    float sum = 0.f;
#pragma unroll
    for (int i = 0; i < 8; ++i) {
        float4 v = vv[i];
        sum += __expf(v.x - mx) + __expf(v.y - mx) + __expf(v.z - mx) + __expf(v.w - mx);
    }
#pragma unroll
    for (int m = 32; m > 0; m >>= 1) sum += __shfl_xor(sum, m);
    if ((t & 63) == 0) red[4 + (t >> 6)] = sum;
    __syncthreads();
    if (t == 0) { mb[bh] = mx; lb[bh] = red[4] + red[5] + red[6] + red[7]; }
}

// ---------------------------------------------------------------- kernel 3: out[b,d] = sum_n w[b,h(d),n] * x[b,n,d]
__global__ __launch_bounds__(256) void out_kernel(
    const float* __restrict__ x, const float* __restrict__ s_buf,
    const float* __restrict__ mb, const float* __restrict__ lb,
    float* __restrict__ out) {
    const int b = blockIdx.x >> 6;      // 16
    const int chunk = blockIdx.x & 63;  // 64 chunks of 128 rows
    const int n0 = chunk * 128;
    const int t = threadIdx.x;
    __shared__ float w[8 * 128];
    for (int i = t; i < 1024; i += 256) {
        int hh = i >> 7, nn = i & 127;
        int bh = b * 8 + hh;
        w[i] = __expf(s_buf[((size_t)bh << 13) + n0 + nn] - mb[bh]) / lb[bh];
    }
    __syncthreads();
    const int rg = t >> 6;            // 4 row-groups
    const int d0 = (t & 63) * 8;      // 8 fp32 per thread -> full 512-wide row per wave
    const float* wh = w + ((d0 >> 6) << 7);
    float acc[8] = {0.f, 0.f, 0.f, 0.f, 0.f, 0.f, 0.f, 0.f};
    for (int nn = rg; nn < 128; nn += 4) {
        const float4* row = (const float4*)(x + (((size_t)(b * 8192 + n0 + nn)) << 9) + d0);
        float4 v0 = row[0];
        float4 v1 = row[1];
        float ww = wh[nn];
        acc[0] += ww * v0.x; acc[1] += ww * v0.y;
        acc[2] += ww * v0.z; acc[3] += ww * v0.w;
        acc[4] += ww * v1.x; acc[5] += ww * v1.y;
        acc[6] += ww * v1.z; acc[7] += ww * v1.w;
    }
#pragma unroll
    for (int j = 0; j < 8; ++j) atomicAdd(&out[b * 512 + d0 + j], acc[j]);
}

// ---------------------------------------------------------------- launch
extern "C" void kernel_launch(void* const* d_in, const int* in_sizes, int n_in,
                              void* d_out, int out_size, void* d_ws, size_t ws_size,
                              hipStream_t stream) {
    const float* x  = (const float*)d_in[0];
    const float* Wk = (const float*)d_in[1];
    const float* Wg = (const float*)d_in[2];
    const float* q  = (const float*)d_in[3];
    float* out = (float*)d_out;

    // ws layout (total ~5.25 MB)
    char* ws = (char*)d_ws;
    unsigned short* wkb = (unsigned short*)ws;                   // 524288 B
    unsigned short* wgb = (unsigned short*)(ws + 524288ull);     // 524288 B
    float* s_buf = (float*)(ws + 1048576ull);                    // 4194304 B
    float* mb = (float*)(ws + 5242880ull);                       // 512 B
    float* lb = (float*)(ws + 5243392ull);                       // 512 B

    hipMemsetAsync(d_out, 0, 512 * B_ * sizeof(float), stream);

    hipLaunchKernelGGL(cvt_kernel, dim3(256), dim3(256), 0, stream, Wk, wkb, (D_ * D_) / 4);
    hipLaunchKernelGGL(cvt_kernel, dim3(256), dim3(256), 0, stream, Wg, wgb, (D_ * D_) / 4);
    hipLaunchKernelGGL(gemm_score_kernel, dim3(2048), dim3(512), 0, stream, x, wkb, wgb, q, s_buf);
    hipLaunchKernelGGL(stats_kernel, dim3(128), dim3(256), 0, stream, s_buf, mb, lb);
    hipLaunchKernelGGL(out_kernel, dim3(1024), dim3(256), 0, stream, x, s_buf, mb, lb, out);
}

// Round 3
// 549.992 us; speedup vs baseline: 1.2332x; 1.2332x over previous
//
#include <hip/hip_runtime.h>
#include <hip/hip_bf16.h>

// Problem constants
#define H_ 8
#define D_ 512
#define DK_ 64
#define B_ 16
#define N_ 8192
#define M_ (B_ * N_)  // 131072 rows

typedef __attribute__((ext_vector_type(8))) short short8;
typedef __attribute__((ext_vector_type(4))) float floatx4;

// ---------------------------------------------------------------- helpers
__device__ __forceinline__ void glds16(const void* g, void* l) {
    // 16B-wide direct global->LDS DMA. LDS dest = wave-uniform base + lane*16.
    __builtin_amdgcn_global_load_lds((const __attribute__((address_space(1))) void*)g,
                                     (__attribute__((address_space(3))) void*)l,
                                     16, 0, 0);
}

__device__ __forceinline__ unsigned short f2bf(float f) {  // RNE
    unsigned u = __float_as_uint(f);
    return (unsigned short)((u + 0x7fffu + ((u >> 16) & 1u)) >> 16);
}

// HW packed fp32x2 -> bf16x2 (RNE), 1 inst per 2 elements (T12 recipe, m240)
__device__ __forceinline__ unsigned cvt_pk(float lo, float hi) {
    unsigned r;
    asm("v_cvt_pk_bf16_f32 %0, %1, %2" : "=v"(r) : "v"(lo), "v"(hi));
    return r;
}

__device__ __forceinline__ short8 pack_bf8(float4 lo, float4 hi) {
    union { unsigned u[4]; short8 s; } tmp;
    tmp.u[0] = cvt_pk(lo.x, lo.y);
    tmp.u[1] = cvt_pk(lo.z, lo.w);
    tmp.u[2] = cvt_pk(hi.x, hi.y);
    tmp.u[3] = cvt_pk(hi.z, hi.w);
    return tmp.s;
}

// ---------------------------------------------------------------- kernel 0: fp32 -> bf16 (weights only, 1 MB total)
__global__ __launch_bounds__(256) void cvt_kernel(const float* __restrict__ src,
                                                  unsigned short* __restrict__ dst, int n4) {
    int i = blockIdx.x * blockDim.x + threadIdx.x;
    int stride = gridDim.x * blockDim.x;
    for (; i < n4; i += stride) {
        float4 v = ((const float4*)src)[i];
        ushort4 o;
        o.x = f2bf(v.x); o.y = f2bf(v.y); o.z = f2bf(v.z); o.w = f2bf(v.w);
        ((ushort4*)dst)[i] = o;
    }
}

// ---------------------------------------------------------------- kernel 1: fused double-GEMM + gate + query-dot
// r0 2-phase skeleton (proven 256us, 2 independent blocks/CU) + grafts:
//  - r1's empirically zero-conflict swizzle: 16B chunk c of row r at slot
//    c ^ (r&7); frag reads slot (q4 ^ (row&7)) ^ (kc*4).
//  - v_cvt_pk_bf16_f32 packing (1 inst / 2 elems, was 3 perm-ops / 2).
//  - single-rcp gated epilogue (no IEEE div sequences).
// BM=128, BNv=256 (128 Wk + 128 Wg cols), BK=64, 256 thr = 4 waves,
// wave tile 64 rows x (64 Wk + 64 Wg) cols. LDS 48KB single-buffered.
__global__ __launch_bounds__(256, 2) void gemm_score_kernel(
    const float* __restrict__ x,             // (M_, 512) fp32
    const unsigned short* __restrict__ wkb,  // (512, 512) bf16
    const unsigned short* __restrict__ wgb,  // (512, 512) bf16
    const float* __restrict__ query,         // (8, 64) fp32
    float* __restrict__ s_buf)               // (B_, H_, N_) fp32
{
    __shared__ __attribute__((aligned(16))) unsigned short lds_a[128 * 64];  // 16 KB
    __shared__ __attribute__((aligned(16))) unsigned short lds_k[128 * 64];  // 16 KB
    __shared__ __attribute__((aligned(16))) unsigned short lds_g[128 * 64];  // 16 KB

    const int t = threadIdx.x;
    const int lane = t & 63;
    const int wave = t >> 6;
    const int wm = wave >> 1, wn = wave & 1;
    const int fr = lane & 15;
    const int q4 = lane >> 4;
    const int sw = fr & 7;

    // XCD-aware remap: 4 jc-siblings of an m-tile -> ids 8 apart -> same XCD.
    const int g = blockIdx.x;          // 0..4095
    const int xcd = g & 7;
    const int s = g >> 3;              // 0..511
    const int jt = s & 3;              // col tile 0..3
    const int mt = ((s >> 2) << 3) | xcd;  // 0..1023
    const int jc = jt * 128;
    const int m0 = mt * 128;

    // ---- A staging: 4 its; it: row = it*32 + (t>>3), chunk c = t&7
    const int ar = t >> 3;   // 0..31
    const int ac = t & 7;
    const float* pA = x + (size_t)(m0 + ar) * 512 + ac * 8;   // + it*32*512 + k0
    const int awoff = ar * 64 + (ac ^ (ar & 7)) * 8;          // shorts; + it*2048
    // (row&7) == (ar&7) since it*32 == 0 mod 8

    // ---- B staging: issue i: slot p = i*256+t: r = p>>3, c = p&7,
    //      source chunk = c ^ (r&7), dest linear p*16B (r1's zero-conflict map)
    int boff[4];
#pragma unroll
    for (int i = 0; i < 4; ++i) {
        int p = i * 256 + t;
        int r = p >> 3;                // 0..127
        int c = (p & 7) ^ (r & 7);
        boff[i] = (jc + r) * 512 + c * 8;   // bf16 elements
    }

    floatx4 acc_k[4][4], acc_g[4][4];
#pragma unroll
    for (int i = 0; i < 4; ++i)
#pragma unroll
        for (int j = 0; j < 4; ++j) { acc_k[i][j] = (floatx4)0.f; acc_g[i][j] = (floatx4)0.f; }

    for (int k0 = 0; k0 < 512; k0 += 64) {
        // B tiles: async DMA (issued first -> drained for free by av-wait FIFO)
#pragma unroll
        for (int i = 0; i < 4; ++i) {
            glds16(wkb + boff[i] + k0, lds_k + (size_t)(i * 256 + t) * 8);
            glds16(wgb + boff[i] + k0, lds_g + (size_t)(i * 256 + t) * 8);
        }
        // A tile: fp32 loads -> cvt_pk bf16 -> swizzled ds_write_b128
        float4 av[8];
#pragma unroll
        for (int it = 0; it < 4; ++it) {
            const float* p = pA + (size_t)it * (32 * 512) + k0;
            av[it * 2]     = *(const float4*)(p);
            av[it * 2 + 1] = *(const float4*)(p + 4);
        }
#pragma unroll
        for (int it = 0; it < 4; ++it)
            *(short8*)&lds_a[it * (32 * 64) + awoff] = pack_bf8(av[it * 2], av[it * 2 + 1]);
        __syncthreads();

#pragma unroll
        for (int kc = 0; kc < 2; ++kc) {
            short8 a[4], bk[4], bg[4];
#pragma unroll
            for (int mi = 0; mi < 4; ++mi) {
                int off = (wm * 64 + mi * 16 + fr) * 64 + (q4 ^ sw) * 8;
                a[mi] = *(const short8*)&lds_a[off ^ (kc * 32)];
            }
#pragma unroll
            for (int ni = 0; ni < 4; ++ni) {
                int off = (wn * 64 + ni * 16 + fr) * 64 + (q4 ^ sw) * 8;
                bk[ni] = *(const short8*)&lds_k[off ^ (kc * 32)];
                bg[ni] = *(const short8*)&lds_g[off ^ (kc * 32)];
            }
#pragma unroll
            for (int mi = 0; mi < 4; ++mi)
#pragma unroll
                for (int ni = 0; ni < 4; ++ni) {
                    acc_k[mi][ni] = __builtin_amdgcn_mfma_f32_16x16x32_bf16(a[mi], bk[ni], acc_k[mi][ni], 0, 0, 0);
                    acc_g[mi][ni] = __builtin_amdgcn_mfma_f32_16x16x32_bf16(a[mi], bg[ni], acc_g[mi][ni], 0, 0, 0);
                }
        }
        __syncthreads();
    }

    // Epilogue: gated = tanh(K)*sigmoid(G) = (e2k-1)*eg / ((e2k+1)*(eg+1)),
    // one fast rcp per element instead of two IEEE divisions.
    // C/D layout: col = lane&15, row = (lane>>4)*4 + reg.
    const int h = jt * 2 + wn;  // this wave's head
    float qv[4];
#pragma unroll
    for (int ni = 0; ni < 4; ++ni) qv[ni] = query[h * 64 + ni * 16 + fr];

#pragma unroll
    for (int mi = 0; mi < 4; ++mi) {
#pragma unroll
        for (int r = 0; r < 4; ++r) {
            float v = 0.f;
#pragma unroll
            for (int ni = 0; ni < 4; ++ni) {
                float kv = acc_k[mi][ni][r];
                float gv = acc_g[mi][ni][r];
                float e2k = fminf(__expf(2.f * kv), 1e18f);   // clamp: den <= ~1e36
                float eg  = fminf(__expf(gv),      1e18f);
                float num = (e2k - 1.f) * eg;
                float den = (e2k + 1.f) * (eg + 1.f);
                v += qv[ni] * num * __builtin_amdgcn_rcpf(den);
            }
            v += __shfl_xor(v, 1);
            v += __shfl_xor(v, 2);
            v += __shfl_xor(v, 4);
            v += __shfl_xor(v, 8);
            if (fr == 0) {
                int mg = m0 + wm * 64 + mi * 16 + q4 * 4 + r;
                int b = mg >> 13, n = mg & 8191;
                s_buf[((size_t)(b * 8 + h) << 13) + n] = v;
            }
        }
    }
}

// ---------------------------------------------------------------- kernel 2: per-(b,h) softmax stats (float4, in-reg two-pass)
// Stores lb = 1/sum so out_kernel multiplies instead of divides.
__global__ __launch_bounds__(256) void stats_kernel(const float* __restrict__ s_buf,
                                                    float* __restrict__ mb, float* __restrict__ lb) {
    const int bh = blockIdx.x;  // 0..127
    const float4* s4 = (const float4*)(s_buf + ((size_t)bh << 13));
    const int t = threadIdx.x;
    float4 vv[8];
    float mx = -3.0e38f;
#pragma unroll
    for (int i = 0; i < 8; ++i) {
        float4 v = s4[t + i * 256];
        vv[i] = v;
        mx = fmaxf(mx, fmaxf(fmaxf(v.x, v.y), fmaxf(v.z, v.w)));
    }
#pragma unroll
    for (int m = 32; m > 0; m >>= 1) mx = fmaxf(mx, __shfl_xor(mx, m));
    __shared__ float red[8];
    if ((t & 63) == 0) red[t >> 6] = mx;
    __syncthreads();
    mx = fmaxf(fmaxf(red[0], red[1]), fmaxf(red[2], red[3]));
    float sum = 0.f;
#pragma unroll
    for (int i = 0; i < 8; ++i) {
        float4 v = vv[i];
        sum += __expf(v.x - mx) + __expf(v.y - mx) + __expf(v.z - mx) + __expf(v.w - mx);
    }
#pragma unroll
    for (int m = 32; m > 0; m >>= 1) sum += __shfl_xor(sum, m);
    if ((t & 63) == 0) red[4 + (t >> 6)] = sum;
    __syncthreads();
    if (t == 0) { mb[bh] = mx; lb[bh] = 1.f / (red[4] + red[5] + red[6] + red[7]); }
}

// ---------------------------------------------------------------- kernel 3: out[b,d] = sum_n w[b,h(d),n] * x[b,n,d]
// 1024 blocks (4/CU, 16 waves/CU). 2-row unroll -> 4 float4 in flight per
// thread. LDS cross-rowgroup reduction -> 512 atomics/block (was 2048).
__global__ __launch_bounds__(256) void out_kernel(
    const float* __restrict__ x, const float* __restrict__ s_buf,
    const float* __restrict__ mb, const float* __restrict__ lb,
    float* __restrict__ out) {
    const int b = blockIdx.x >> 6;      // 16
    const int chunk = blockIdx.x & 63;  // 64 chunks of 128 rows
    const int n0 = chunk * 128;
    const int t = threadIdx.x;
    __shared__ float w[8 * 128];        // 4 KB
    __shared__ float red[3 * 512];      // 6 KB
    for (int i = t; i < 1024; i += 256) {
        int hh = i >> 7, nn = i & 127;
        int bh = b * 8 + hh;
        w[i] = __expf(s_buf[((size_t)bh << 13) + n0 + nn] - mb[bh]) * lb[bh];  // lb = 1/sum
    }
    __syncthreads();
    const int rg = t >> 6;            // 4 row-groups
    const int d0 = (t & 63) * 8;      // 8 fp32 per thread -> full 512-wide row per wave
    const float* wh = w + ((d0 >> 6) << 7);
    const float* xb = x + (((size_t)(b * 8192 + n0)) << 9) + d0;
    float acc[8] = {0.f, 0.f, 0.f, 0.f, 0.f, 0.f, 0.f, 0.f};
    for (int i = 0; i < 32; i += 2) {
        const int n1 = rg + i * 4;
        const int n2 = n1 + 4;
        const float4* r1p = (const float4*)(xb + ((size_t)n1 << 9));
        const float4* r2p = (const float4*)(xb + ((size_t)n2 << 9));
        float4 a0 = r1p[0];
        float4 a1 = r1p[1];
        float4 b0 = r2p[0];
        float4 b1 = r2p[1];
        float w1 = wh[n1];   // wave-uniform -> LDS broadcast
        float w2 = wh[n2];
        acc[0] += w1 * a0.x; acc[1] += w1 * a0.y; acc[2] += w1 * a0.z; acc[3] += w1 * a0.w;
        acc[4] += w1 * a1.x; acc[5] += w1 * a1.y; acc[6] += w1 * a1.z; acc[7] += w1 * a1.w;
        acc[0] += w2 * b0.x; acc[1] += w2 * b0.y; acc[2] += w2 * b0.z; acc[3] += w2 * b0.w;
        acc[4] += w2 * b1.x; acc[5] += w2 * b1.y; acc[6] += w2 * b1.z; acc[7] += w2 * b1.w;
    }
    if (rg != 0) {
#pragma unroll
        for (int j = 0; j < 8; ++j) red[(rg - 1) * 512 + (t & 63) * 8 + j] = acc[j];
    }
    __syncthreads();
    if (rg == 0) {
#pragma unroll
        for (int j = 0; j < 8; ++j) {
            float v = acc[j] + red[(t & 63) * 8 + j] + red[512 + (t & 63) * 8 + j]
                    + red[1024 + (t & 63) * 8 + j];
            atomicAdd(&out[b * 512 + d0 + j], v);
        }
    }
}

// ---------------------------------------------------------------- launch
extern "C" void kernel_launch(void* const* d_in, const int* in_sizes, int n_in,
                              void* d_out, int out_size, void* d_ws, size_t ws_size,
                              hipStream_t stream) {
    const float* x  = (const float*)d_in[0];
    const float* Wk = (const float*)d_in[1];
    const float* Wg = (const float*)d_in[2];
    const float* q  = (const float*)d_in[3];
    float* out = (float*)d_out;

    // ws layout (total ~5.25 MB)
    char* ws = (char*)d_ws;
    unsigned short* wkb = (unsigned short*)ws;                   // 524288 B
    unsigned short* wgb = (unsigned short*)(ws + 524288ull);     // 524288 B
    float* s_buf = (float*)(ws + 1048576ull);                    // 4194304 B
    float* mb = (float*)(ws + 5242880ull);                       // 512 B
    float* lb = (float*)(ws + 5243392ull);                       // 512 B

    hipMemsetAsync(d_out, 0, 512 * B_ * sizeof(float), stream);

    hipLaunchKernelGGL(cvt_kernel, dim3(256), dim3(256), 0, stream, Wk, wkb, (D_ * D_) / 4);
    hipLaunchKernelGGL(cvt_kernel, dim3(256), dim3(256), 0, stream, Wg, wgb, (D_ * D_) / 4);
    hipLaunchKernelGGL(gemm_score_kernel, dim3(4096), dim3(256), 0, stream, x, wkb, wgb, q, s_buf);
    hipLaunchKernelGGL(stats_kernel, dim3(128), dim3(256), 0, stream, s_buf, mb, lb);
    hipLaunchKernelGGL(out_kernel, dim3(1024), dim3(256), 0, stream, x, s_buf, mb, lb, out);
}